// Round 4
// baseline (264.284 us; speedup 1.0000x reference)
//
#include <hip/hip_runtime.h>

// FFTConv fused: y[b,d,:] = (h[d] (*) x[b,d])[0:L] + x[b,d]*B[d]
// d_model=1024, L=8192, batch=2, fp32. One 1024-thread block per channel.
// Radix-4 DIF forward (digit-reversed spectrum, never reordered), pointwise
// multiply fused in registers between the last forward stage and the first
// inverse stage (both twiddle==1, same 4 elements), stage-exact inverse ->
// natural-order output. Batch packed z = x0 + i*x1. Residual folded into
// spectrum: y = ifft(X*(H+B)/N).
// Twiddles via raw v_sin_f32/v_cos_f32 (input in REVOLUTIONS — exact for
// rev = j*2^-(lq+2)); avoids __sincosf's pointer out-param scratch traffic.

#define L_SEQ   8192
#define N_FFT   16384
#define D_MODEL 1024
#define NTH     1024

// XOR swizzle on float2 index: caps LDS bank conflicts at ~4-way for all
// power-of-2 strides, keeps stride-1 access conflict-free.
#define SWZ(i) ((i) ^ (((i) >> 4) & 15))

__device__ __forceinline__ float2 cmul(float2 a, float2 b) {
    return make_float2(a.x * b.x - a.y * b.y, a.x * b.y + a.y * b.x);
}

// Hardware sin/cos of (2*pi*rev). No range reduction needed for |rev| < 1.
__device__ __forceinline__ float2 hw_cis(float rev) {
    return make_float2(__builtin_amdgcn_cosf(rev), __builtin_amdgcn_sinf(rev));
}

// One LDS radix-4 stage (s in 0..5; stage 6 is done in registers by callers).
// SIGN=-1: forward DIF. SIGN=+1: exact inverse of the forward stage.
template <int SIGN>
__device__ __forceinline__ void fft_stage(float2* __restrict__ z, const int tid, const int s) {
    const int lq = 12 - 2 * s;       // log2(q), q = butterfly span
    const int q  = 1 << lq;
    // twiddle angle = SIGN * 2*pi * j / (4q)  ->  revolutions = SIGN * j * 2^-(lq+2)
    const float revc = (float)SIGN / (float)(1 << (lq + 2));
#pragma unroll
    for (int r = 0; r < 4; ++r) {
        const int t = tid + r * NTH;             // butterfly id 0..4095
        const int j = t & (q - 1);
        const int base = ((t >> lq) << (lq + 2)) | j;
        const int p0 = SWZ(base);
        const int p1 = SWZ(base + q);
        const int p2 = SWZ(base + 2 * q);
        const int p3 = SWZ(base + 3 * q);
        const float2 w1 = hw_cis(revc * (float)j);
        const float2 w2 = cmul(w1, w1);
        const float2 w3 = cmul(w2, w1);
        if (SIGN < 0) {
            const float2 a0 = z[p0], a1 = z[p1], a2 = z[p2], a3 = z[p3];
            const float2 t0 = make_float2(a0.x + a2.x, a0.y + a2.y);
            const float2 t1 = make_float2(a0.x - a2.x, a0.y - a2.y);
            const float2 t2 = make_float2(a1.x + a3.x, a1.y + a3.y);
            const float2 t3 = make_float2(a1.x - a3.x, a1.y - a3.y);
            const float2 A0 = make_float2(t0.x + t2.x, t0.y + t2.y);
            const float2 A2 = make_float2(t0.x - t2.x, t0.y - t2.y);
            const float2 A1 = make_float2(t1.x + t3.y, t1.y - t3.x);   // t1 - i*t3
            const float2 A3 = make_float2(t1.x - t3.y, t1.y + t3.x);   // t1 + i*t3
            z[p0] = A0;
            z[p1] = cmul(A1, w1);
            z[p2] = cmul(A2, w2);
            z[p3] = cmul(A3, w3);
        } else {
            const float2 b0 = z[p0], b1 = z[p1], b2 = z[p2], b3 = z[p3];
            const float2 A0 = b0;
            const float2 A1 = cmul(b1, w1);   // w = conj(forward w) via SIGN
            const float2 A2 = cmul(b2, w2);
            const float2 A3 = cmul(b3, w3);
            const float2 u0 = make_float2(A0.x + A2.x, A0.y + A2.y);
            const float2 u1 = make_float2(A0.x - A2.x, A0.y - A2.y);
            const float2 u2 = make_float2(A1.x + A3.x, A1.y + A3.y);
            const float2 u3 = make_float2(A1.x - A3.x, A1.y - A3.y);
            z[p0] = make_float2(u0.x + u2.x, u0.y + u2.y);
            z[p2] = make_float2(u0.x - u2.x, u0.y - u2.y);
            z[p1] = make_float2(u1.x - u3.y, u1.y + u3.x);             // u1 + i*u3
            z[p3] = make_float2(u1.x + u3.y, u1.y - u3.x);             // u1 - i*u3
        }
    }
    __syncthreads();
}

__global__ void __launch_bounds__(NTH, 4) fftconv_fused_kernel(
        const float* __restrict__ h, const float* __restrict__ x,
        const float* __restrict__ Bg, float* __restrict__ y) {
    extern __shared__ float2 z[];
    const int d = blockIdx.x;
    const int tid = threadIdx.x;

    const float invn = 1.0f / (float)N_FFT;
    const float Bscaled = Bg[d] * invn;

    // ---- load + FFT of filter row (6 LDS stages; stage 7 captured in regs) ----
    const float* hrow = h + (size_t)d * L_SEQ;
#pragma unroll
    for (int r = 0; r < 8; ++r) {
        const int t = tid + r * NTH;
        z[SWZ(t)]         = make_float2(hrow[t], 0.0f);
        z[SWZ(t + L_SEQ)] = make_float2(0.0f, 0.0f);
    }
    __syncthreads();
#pragma unroll
    for (int s = 0; s < 6; ++s) fft_stage<-1>(z, tid, s);

    // final forward stage (q=1, twiddle==1) in registers -> Hreg = (H + B)/N
    float2 Hreg[16];
#pragma unroll
    for (int r = 0; r < 4; ++r) {
        const int b = 4 * (tid + r * NTH);
        const float2 a0 = z[SWZ(b)], a1 = z[SWZ(b + 1)], a2 = z[SWZ(b + 2)], a3 = z[SWZ(b + 3)];
        const float2 t0 = make_float2(a0.x + a2.x, a0.y + a2.y);
        const float2 t1 = make_float2(a0.x - a2.x, a0.y - a2.y);
        const float2 t2 = make_float2(a1.x + a3.x, a1.y + a3.y);
        const float2 t3 = make_float2(a1.x - a3.x, a1.y - a3.y);
        Hreg[4 * r + 0] = make_float2((t0.x + t2.x) * invn + Bscaled, (t0.y + t2.y) * invn);
        Hreg[4 * r + 1] = make_float2((t1.x + t3.y) * invn + Bscaled, (t1.y - t3.x) * invn);
        Hreg[4 * r + 2] = make_float2((t0.x - t2.x) * invn + Bscaled, (t0.y - t2.y) * invn);
        Hreg[4 * r + 3] = make_float2((t1.x - t3.y) * invn + Bscaled, (t1.y + t3.x) * invn);
    }
    __syncthreads();   // all stage-6 reads done before z is overwritten

    // ---- load + FFT of batch-packed signal z = x0 + i*x1 ----
    const float* x0 = x + (size_t)d * L_SEQ;
    const float* x1 = x + (size_t)(D_MODEL + d) * L_SEQ;
#pragma unroll
    for (int r = 0; r < 8; ++r) {
        const int t = tid + r * NTH;
        z[SWZ(t)]         = make_float2(x0[t], x1[t]);
        z[SWZ(t + L_SEQ)] = make_float2(0.0f, 0.0f);
    }
    __syncthreads();
#pragma unroll
    for (int s = 0; s < 6; ++s) fft_stage<-1>(z, tid, s);

    // ---- fused middle in registers: fwd stage 7 -> pointwise -> inv stage 1 ----
#pragma unroll
    for (int r = 0; r < 4; ++r) {
        const int b = 4 * (tid + r * NTH);
        const int p0 = SWZ(b), p1 = SWZ(b + 1), p2 = SWZ(b + 2), p3 = SWZ(b + 3);
        const float2 a0 = z[p0], a1 = z[p1], a2 = z[p2], a3 = z[p3];
        // forward radix-4 (w == 1)
        const float2 t0 = make_float2(a0.x + a2.x, a0.y + a2.y);
        const float2 t1 = make_float2(a0.x - a2.x, a0.y - a2.y);
        const float2 t2 = make_float2(a1.x + a3.x, a1.y + a3.y);
        const float2 t3 = make_float2(a1.x - a3.x, a1.y - a3.y);
        const float2 A0 = make_float2(t0.x + t2.x, t0.y + t2.y);
        const float2 A2 = make_float2(t0.x - t2.x, t0.y - t2.y);
        const float2 A1 = make_float2(t1.x + t3.y, t1.y - t3.x);
        const float2 A3 = make_float2(t1.x - t3.y, t1.y + t3.x);
        // pointwise multiply with (H+B)/N
        const float2 P0 = cmul(A0, Hreg[4 * r + 0]);
        const float2 P1 = cmul(A1, Hreg[4 * r + 1]);
        const float2 P2 = cmul(A2, Hreg[4 * r + 2]);
        const float2 P3 = cmul(A3, Hreg[4 * r + 3]);
        // inverse radix-4 (w == 1)
        const float2 u0 = make_float2(P0.x + P2.x, P0.y + P2.y);
        const float2 u1 = make_float2(P0.x - P2.x, P0.y - P2.y);
        const float2 u2 = make_float2(P1.x + P3.x, P1.y + P3.y);
        const float2 u3 = make_float2(P1.x - P3.x, P1.y - P3.y);
        z[p0] = make_float2(u0.x + u2.x, u0.y + u2.y);
        z[p2] = make_float2(u0.x - u2.x, u0.y - u2.y);
        z[p1] = make_float2(u1.x - u3.y, u1.y + u3.x);
        z[p3] = make_float2(u1.x + u3.y, u1.y - u3.x);
    }
    __syncthreads();

    // ---- remaining 6 inverse stages (s = 5 .. 0) ----
#pragma unroll
    for (int si = 0; si < 6; ++si) fft_stage<+1>(z, tid, 5 - si);

    // ---- store (residual already folded via spectrum) ----
    float* y0 = y + (size_t)d * L_SEQ;
    float* y1 = y + (size_t)(D_MODEL + d) * L_SEQ;
#pragma unroll
    for (int r = 0; r < 8; ++r) {
        const int t = tid + r * NTH;
        const float2 v = z[SWZ(t)];
        y0[t] = v.x;
        y1[t] = v.y;
    }
}

extern "C" void kernel_launch(void* const* d_in, const int* in_sizes, int n_in,
                              void* d_out, int out_size, void* d_ws, size_t ws_size,
                              hipStream_t stream) {
    const float* h = (const float*)d_in[0];   // (1024, 8192)
    const float* x = (const float*)d_in[1];   // (2, 1024, 8192)
    const float* B = (const float*)d_in[2];   // (1024, 1)
    float* y = (float*)d_out;                 // (2, 1024, 8192)

    const size_t lds_bytes = (size_t)N_FFT * sizeof(float2);  // 128 KB

    fftconv_fused_kernel<<<dim3(D_MODEL), dim3(NTH), lds_bytes, stream>>>(h, x, B, y);
}